// Round 1
// baseline (402.099 us; speedup 1.0000x reference)
//
#include <hip/hip_runtime.h>
#include <stdint.h>

// NeZha self-attention, B=4 S=1024 H=1024 NH=16 HD=64 MAX_REL=127.
// Key structure: rel_pos[q,k,:] == table[clip(k-q,-127,127)+127,:], table is 255x64.
//  - score rel term:  gather from R = Q @ table^T            (per (b,h,q): R[q,j])
//  - ctx rel term:    Pagg @ table, Pagg = banded prob aggregation
// Two-pass softmax: pass A -> exact (m,l); pass B -> P, O=P@V, Pagg, +Pagg@table^T.

typedef __bf16 bf16x8 __attribute__((ext_vector_type(8)));
typedef float f32x4 __attribute__((ext_vector_type(4)));
typedef uint16_t u16x8 __attribute__((ext_vector_type(8)));

__device__ __forceinline__ uint16_t f2bf(float f) {
    uint32_t u = __builtin_bit_cast(uint32_t, f);
    return (uint16_t)((u + 0x7FFFu + ((u >> 16) & 1u)) >> 16);
}
__device__ __forceinline__ float bf2f(uint16_t h) {
    uint32_t u = ((uint32_t)h) << 16;
    return __builtin_bit_cast(float, u);
}
__device__ __forceinline__ f32x4 mfma16(bf16x8 a, bf16x8 b, f32x4 c) {
    return __builtin_amdgcn_mfma_f32_16x16x32_bf16(a, b, c, 0, 0, 0);
}

// ---------------- cast fp32 -> bf16 (vectorized, 8 elems/thread) ----------------
__global__ void k_cast_bf16(const float* __restrict__ in, uint16_t* __restrict__ out, int n8) {
    int i = blockIdx.x * 256 + threadIdx.x;
    if (i >= n8) return;
    float4 a = ((const float4*)in)[2 * i];
    float4 b = ((const float4*)in)[2 * i + 1];
    u16x8 o;
    o[0] = f2bf(a.x); o[1] = f2bf(a.y); o[2] = f2bf(a.z); o[3] = f2bf(a.w);
    o[4] = f2bf(b.x); o[5] = f2bf(b.y); o[6] = f2bf(b.z); o[7] = f2bf(b.w);
    ((u16x8*)out)[i] = o;
}

// ---------------- extract sinusoid table from rel_pos ----------------
// table[j][d] = rel_pos[512][512 + j - 127][d], j in [0,254]; row 255 zeroed.
__global__ void k_table(const float* __restrict__ rel, uint16_t* __restrict__ tab,
                        uint16_t* __restrict__ tabT) {
    for (int idx = threadIdx.x; idx < 256 * 64; idx += 256) {
        int j = idx >> 6, d = idx & 63;
        float v = 0.0f;
        if (j < 255) v = rel[((size_t)512 * 1024 + (512 + j - 127)) * 64 + d];
        uint16_t h = f2bf(v);
        tab[j * 64 + d] = h;       // [256][64]  (B^T layout for R-GEMM)
        tabT[d * 256 + j] = h;     // [64][256]  (B^T layout for Pagg-GEMM)
    }
}

// ---------------- QKV projection GEMM: [4096,1024] @ W[n][k] -> head layout ------
// out[(b*16+h)*1024 + s][d] bf16, +bias.  128x128 tile, BK=32, 4 waves (2x2).
__launch_bounds__(256)
__global__ void k_gemm_qkv(const uint16_t* __restrict__ A, const uint16_t* __restrict__ Wt,
                           const float* __restrict__ bias, uint16_t* __restrict__ dst) {
    __shared__ uint16_t As[128 * 40];  // pad 32->40: 2-way bank conflicts only
    __shared__ uint16_t Bs[128 * 40];
    int m0 = blockIdx.x * 128, n0 = blockIdx.y * 128;
    int tid = threadIdx.x;
    int w = tid >> 6, l = tid & 63, lg = l >> 4, ln = l & 15;
    int wm = w >> 1, wn = w & 1;
    f32x4 acc[4][4] = {};
    for (int kt = 0; kt < 32; ++kt) {
        int k0 = kt * 32;
        __syncthreads();
#pragma unroll
        for (int c = 0; c < 2; ++c) {
            int idx = c * 256 + tid;
            int row = idx >> 2, seg = idx & 3;
            *(u16x8*)&As[row * 40 + seg * 8] =
                *(const u16x8*)(A + (size_t)(m0 + row) * 1024 + k0 + seg * 8);
            *(u16x8*)&Bs[row * 40 + seg * 8] =
                *(const u16x8*)(Wt + (size_t)(n0 + row) * 1024 + k0 + seg * 8);
        }
        __syncthreads();
        bf16x8 af[4], bfr[4];
#pragma unroll
        for (int mi = 0; mi < 4; ++mi)
            af[mi] = __builtin_bit_cast(bf16x8,
                *(const u16x8*)&As[(wm * 64 + mi * 16 + ln) * 40 + lg * 8]);
#pragma unroll
        for (int ni = 0; ni < 4; ++ni)
            bfr[ni] = __builtin_bit_cast(bf16x8,
                *(const u16x8*)&Bs[(wn * 64 + ni * 16 + ln) * 40 + lg * 8]);
#pragma unroll
        for (int mi = 0; mi < 4; ++mi)
#pragma unroll
            for (int ni = 0; ni < 4; ++ni)
                acc[mi][ni] = mfma16(af[mi], bfr[ni], acc[mi][ni]);
    }
#pragma unroll
    for (int ni = 0; ni < 4; ++ni) {
        int n = n0 + wn * 64 + ni * 16 + ln;
        float bv = bias[n];
        int h = n >> 6, d = n & 63;
#pragma unroll
        for (int mi = 0; mi < 4; ++mi) {
#pragma unroll
            for (int r = 0; r < 4; ++r) {
                int mrow = m0 + wm * 64 + mi * 16 + lg * 4 + r;
                int b = mrow >> 10, s = mrow & 1023;
                dst[(((size_t)(b * 16 + h)) * 1024 + s) * 64 + d] =
                    f2bf(acc[mi][ni][r] + bv);
            }
        }
    }
}

// ---------------- V transpose: [bh][s][d] -> VT [bh][d][s] ----------------
__global__ void k_transpose_v(const uint16_t* __restrict__ v, uint16_t* __restrict__ vt) {
    __shared__ uint16_t T[64][72];
    int bid = blockIdx.x;
    int bh = bid >> 4, s0 = (bid & 15) * 64;
    int tid = threadIdx.x;
    int row = tid >> 2, c0 = (tid & 3) * 16;
    const uint16_t* src = v + ((size_t)bh * 1024 + s0 + row) * 64 + c0;
    u16x8 a = *(const u16x8*)src, b = *(const u16x8*)(src + 8);
#pragma unroll
    for (int e = 0; e < 8; ++e) { T[row][c0 + e] = a[e]; T[row][c0 + 8 + e] = b[e]; }
    __syncthreads();
    u16x8 o0, o1;
#pragma unroll
    for (int e = 0; e < 8; ++e) { o0[e] = T[c0 + e][row]; o1[e] = T[c0 + 8 + e][row]; }
    uint16_t* dstp = vt + ((size_t)bh * 64 + row) * 1024 + s0 + c0;
    *(u16x8*)dstp = o0;
    *(u16x8*)(dstp + 8) = o1;
}

// ---------------- R = Q @ table^T : [65536,64] @ [64,256] -> bf16 [65536,256] ----
__launch_bounds__(256)
__global__ void k_r_gemm(const uint16_t* __restrict__ q, const uint16_t* __restrict__ tab,
                         uint16_t* __restrict__ R) {
    __shared__ uint16_t Qs[64 * 72];
    int m0 = blockIdx.x * 64;
    int tid = threadIdx.x;
    int w = tid >> 6, l = tid & 63, lg = l >> 4, ln = l & 15;
#pragma unroll
    for (int c = 0; c < 2; ++c) {
        int idx = c * 256 + tid; int row = idx >> 3, seg = idx & 7;
        *(u16x8*)&Qs[row * 72 + seg * 8] =
            *(const u16x8*)(q + (size_t)(m0 + row) * 64 + seg * 8);
    }
    __syncthreads();
    bf16x8 aq[4][2];
#pragma unroll
    for (int mi = 0; mi < 4; ++mi)
#pragma unroll
        for (int ks = 0; ks < 2; ++ks)
            aq[mi][ks] = __builtin_bit_cast(bf16x8,
                *(const u16x8*)&Qs[(mi * 16 + ln) * 72 + ks * 32 + lg * 8]);
    f32x4 acc[4][4] = {};
#pragma unroll
    for (int ni = 0; ni < 4; ++ni) {
        int j = w * 64 + ni * 16 + ln;
#pragma unroll
        for (int ks = 0; ks < 2; ++ks) {
            bf16x8 bt = __builtin_bit_cast(bf16x8,
                *(const u16x8*)(tab + j * 64 + ks * 32 + lg * 8));
#pragma unroll
            for (int mi = 0; mi < 4; ++mi)
                acc[mi][ni] = mfma16(aq[mi][ks], bt, acc[mi][ni]);
        }
    }
#pragma unroll
    for (int ni = 0; ni < 4; ++ni)
#pragma unroll
        for (int mi = 0; mi < 4; ++mi)
#pragma unroll
            for (int r = 0; r < 4; ++r)
                R[(size_t)(m0 + mi * 16 + lg * 4 + r) * 256 + w * 64 + ni * 16 + ln] =
                    f2bf(acc[mi][ni][r]);
}

// ---------------- pass A: exact row max m and denom l ----------------
// block = (b,h,q-tile of 64); wave w owns q rows [w*16, w*16+16)
__launch_bounds__(256)
__global__ void k_attn_ml(const uint16_t* __restrict__ qb, const uint16_t* __restrict__ kb,
                          const uint16_t* __restrict__ Rb, float* __restrict__ mout,
                          float* __restrict__ lout) {
    __shared__ uint16_t Qs[64 * 72];
    __shared__ uint16_t Ks[64 * 72];
    __shared__ uint16_t Rs[64 * 264];
    int bid = blockIdx.x;
    int bh = bid >> 4, q0 = (bid & 15) * 64;
    int tid = threadIdx.x;
    int w = tid >> 6, l = tid & 63, lg = l >> 4, ln = l & 15;
    const uint16_t* qbase = qb + ((size_t)bh * 1024 + q0) * 64;
#pragma unroll
    for (int c = 0; c < 2; ++c) {
        int idx = c * 256 + tid; int row = idx >> 3, seg = idx & 7;
        *(u16x8*)&Qs[row * 72 + seg * 8] = *(const u16x8*)(qbase + row * 64 + seg * 8);
    }
    const uint16_t* rbase = Rb + ((size_t)bh * 1024 + q0) * 256;
#pragma unroll
    for (int c = 0; c < 8; ++c) {
        int idx = c * 256 + tid; int row = idx >> 5, seg = idx & 31;
        *(u16x8*)&Rs[row * 264 + seg * 8] = *(const u16x8*)(rbase + row * 256 + seg * 8);
    }
    __syncthreads();
    bf16x8 aq[2];
#pragma unroll
    for (int ks = 0; ks < 2; ++ks)
        aq[ks] = __builtin_bit_cast(bf16x8,
            *(const u16x8*)&Qs[(w * 16 + ln) * 72 + ks * 32 + lg * 8]);
    float mreg[4] = {-1e30f, -1e30f, -1e30f, -1e30f};
    float lreg[4] = {0.f, 0.f, 0.f, 0.f};
    for (int kt = 0; kt < 16; ++kt) {
        __syncthreads();
        const uint16_t* kbase = kb + ((size_t)bh * 1024 + kt * 64) * 64;
#pragma unroll
        for (int c = 0; c < 2; ++c) {
            int idx = c * 256 + tid; int row = idx >> 3, seg = idx & 7;
            *(u16x8*)&Ks[row * 72 + seg * 8] = *(const u16x8*)(kbase + row * 64 + seg * 8);
        }
        __syncthreads();
        float sv[4][4];
#pragma unroll
        for (int nt = 0; nt < 4; ++nt) {
            f32x4 acc = {0.f, 0.f, 0.f, 0.f};
#pragma unroll
            for (int ks = 0; ks < 2; ++ks) {
                bf16x8 bk = __builtin_bit_cast(bf16x8,
                    *(const u16x8*)&Ks[(nt * 16 + ln) * 72 + ks * 32 + lg * 8]);
                acc = mfma16(aq[ks], bk, acc);
            }
            int kcol = kt * 64 + nt * 16 + ln;
#pragma unroll
            for (int r = 0; r < 4; ++r) {
                int lrow = w * 16 + lg * 4 + r;
                int dj = kcol - (q0 + lrow);
                int djc = dj < -127 ? -127 : (dj > 127 ? 127 : dj);
                float rel = bf2f(Rs[lrow * 264 + djc + 127]);
                sv[nt][r] = (acc[r] + rel) * 0.125f;
            }
        }
#pragma unroll
        for (int r = 0; r < 4; ++r) {
            float tm = fmaxf(fmaxf(sv[0][r], sv[1][r]), fmaxf(sv[2][r], sv[3][r]));
#pragma unroll
            for (int msk = 1; msk < 16; msk <<= 1) tm = fmaxf(tm, __shfl_xor(tm, msk, 16));
            float mnew = fmaxf(mreg[r], tm);
            float se = __expf(sv[0][r] - mnew) + __expf(sv[1][r] - mnew) +
                       __expf(sv[2][r] - mnew) + __expf(sv[3][r] - mnew);
#pragma unroll
            for (int msk = 1; msk < 16; msk <<= 1) se += __shfl_xor(se, msk, 16);
            lreg[r] = lreg[r] * __expf(mreg[r] - mnew) + se;
            mreg[r] = mnew;
        }
    }
    if (ln == 0) {
#pragma unroll
        for (int r = 0; r < 4; ++r) {
            int gi = bh * 1024 + q0 + w * 16 + lg * 4 + r;
            mout[gi] = mreg[r];
            lout[gi] = lreg[r];
        }
    }
}

// ---------------- pass B: exact P, O = P@V + Pagg@table^T ----------------
__launch_bounds__(256)
__global__ void k_attn_out(const uint16_t* __restrict__ qb, const uint16_t* __restrict__ kb,
                           const uint16_t* __restrict__ vtb, const uint16_t* __restrict__ Rb,
                           const uint16_t* __restrict__ tabT, const float* __restrict__ mbuf,
                           const float* __restrict__ lbuf, float* __restrict__ out) {
    __shared__ uint16_t Ks[64 * 72];
    __shared__ uint16_t Vs[64 * 72];   // VT tile [d][k]
    __shared__ uint16_t Ps[64 * 72];   // also used to stage Q at start
    __shared__ uint16_t Rs[64 * 264];
    __shared__ float Pagg[64 * 260];   // stride 260: 16B-aligned rows, banks rotate
    int bid = blockIdx.x;
    int bh = bid >> 4, q0 = (bid & 15) * 64;
    int tid = threadIdx.x;
    int w = tid >> 6, l = tid & 63, lg = l >> 4, ln = l & 15;
    const uint16_t* qbase = qb + ((size_t)bh * 1024 + q0) * 64;
#pragma unroll
    for (int c = 0; c < 2; ++c) {
        int idx = c * 256 + tid; int row = idx >> 3, seg = idx & 7;
        *(u16x8*)&Ps[row * 72 + seg * 8] = *(const u16x8*)(qbase + row * 64 + seg * 8);
    }
    const uint16_t* rbase = Rb + ((size_t)bh * 1024 + q0) * 256;
#pragma unroll
    for (int c = 0; c < 8; ++c) {
        int idx = c * 256 + tid; int row = idx >> 5, seg = idx & 31;
        *(u16x8*)&Rs[row * 264 + seg * 8] = *(const u16x8*)(rbase + row * 256 + seg * 8);
    }
    for (int idx = tid; idx < 64 * 260; idx += 256) Pagg[idx] = 0.f;
    __syncthreads();
    bf16x8 aq[2];
#pragma unroll
    for (int ks = 0; ks < 2; ++ks)
        aq[ks] = __builtin_bit_cast(bf16x8,
            *(const u16x8*)&Ps[(w * 16 + ln) * 72 + ks * 32 + lg * 8]);
    float mreg[4], rinv[4];
#pragma unroll
    for (int r = 0; r < 4; ++r) {
        int gi = bh * 1024 + q0 + w * 16 + lg * 4 + r;
        mreg[r] = mbuf[gi];
        rinv[r] = 1.0f / lbuf[gi];
    }
    f32x4 oacc[4] = {};
    for (int kt = 0; kt < 16; ++kt) {
        __syncthreads();
        const uint16_t* kbase = kb + ((size_t)bh * 1024 + kt * 64) * 64;
        const uint16_t* vtbase = vtb + ((size_t)bh * 64) * 1024 + kt * 64;
#pragma unroll
        for (int c = 0; c < 2; ++c) {
            int idx = c * 256 + tid; int row = idx >> 3, seg = idx & 7;
            *(u16x8*)&Ks[row * 72 + seg * 8] = *(const u16x8*)(kbase + row * 64 + seg * 8);
            *(u16x8*)&Vs[row * 72 + seg * 8] =
                *(const u16x8*)(vtbase + (size_t)row * 1024 + seg * 8);
        }
        __syncthreads();
        float slo[4] = {0, 0, 0, 0}, shi[4] = {0, 0, 0, 0};
#pragma unroll
        for (int nt = 0; nt < 4; ++nt) {
            f32x4 acc = {0.f, 0.f, 0.f, 0.f};
#pragma unroll
            for (int ks = 0; ks < 2; ++ks) {
                bf16x8 bk = __builtin_bit_cast(bf16x8,
                    *(const u16x8*)&Ks[(nt * 16 + ln) * 72 + ks * 32 + lg * 8]);
                acc = mfma16(aq[ks], bk, acc);
            }
            int kcol = kt * 64 + nt * 16 + ln;
#pragma unroll
            for (int r = 0; r < 4; ++r) {
                int lrow = w * 16 + lg * 4 + r;
                int dj = kcol - (q0 + lrow);
                int djc = dj < -127 ? -127 : (dj > 127 ? 127 : dj);
                float rel = bf2f(Rs[lrow * 264 + djc + 127]);
                float s = (acc[r] + rel) * 0.125f;
                float P = __expf(s - mreg[r]) * rinv[r];
                Ps[lrow * 72 + nt * 16 + ln] = f2bf(P);
                if (dj <= -127) slo[r] += P;           // clips to j=0
                else if (dj >= 127) shi[r] += P;       // clips to j=254
                else Pagg[lrow * 260 + dj + 127] = P;  // bijective band, j in [1,253]
            }
        }
#pragma unroll
        for (int r = 0; r < 4; ++r) {
            float a = slo[r], b = shi[r];
#pragma unroll
            for (int msk = 1; msk < 16; msk <<= 1) {
                a += __shfl_xor(a, msk, 16);
                b += __shfl_xor(b, msk, 16);
            }
            if (ln == 0) {
                int lrow = w * 16 + lg * 4 + r;
                Pagg[lrow * 260 + 0] += a;
                Pagg[lrow * 260 + 254] += b;
            }
        }
        // O += P @ V  (A rows = this wave's 16 q rows only -> no cross-wave barrier)
#pragma unroll
        for (int ks = 0; ks < 2; ++ks) {
            bf16x8 ap = __builtin_bit_cast(bf16x8,
                *(const u16x8*)&Ps[(w * 16 + ln) * 72 + ks * 32 + lg * 8]);
#pragma unroll
            for (int nt = 0; nt < 4; ++nt) {
                bf16x8 bv = __builtin_bit_cast(bf16x8,
                    *(const u16x8*)&Vs[(nt * 16 + ln) * 72 + ks * 32 + lg * 8]);
                oacc[nt] = mfma16(ap, bv, oacc[nt]);
            }
        }
    }
    // O += Pagg @ table  (B^T = tabT[d][j]); Pagg rows are wave-local
#pragma unroll
    for (int ks = 0; ks < 8; ++ks) {
        f32x4 p0 = *(const f32x4*)&Pagg[(w * 16 + ln) * 260 + ks * 32 + lg * 8];
        f32x4 p1 = *(const f32x4*)&Pagg[(w * 16 + ln) * 260 + ks * 32 + lg * 8 + 4];
        u16x8 u;
        u[0] = f2bf(p0[0]); u[1] = f2bf(p0[1]); u[2] = f2bf(p0[2]); u[3] = f2bf(p0[3]);
        u[4] = f2bf(p1[0]); u[5] = f2bf(p1[1]); u[6] = f2bf(p1[2]); u[7] = f2bf(p1[3]);
        bf16x8 ap = __builtin_bit_cast(bf16x8, u);
#pragma unroll
        for (int nt = 0; nt < 4; ++nt) {
            bf16x8 bt = __builtin_bit_cast(bf16x8,
                *(const u16x8*)(tabT + (size_t)(nt * 16 + ln) * 256 + ks * 32 + lg * 8));
            oacc[nt] = mfma16(ap, bt, oacc[nt]);
        }
    }
    int b = bh >> 4, h = bh & 15;
#pragma unroll
    for (int nt = 0; nt < 4; ++nt) {
        int d = nt * 16 + ln;
#pragma unroll
        for (int r = 0; r < 4; ++r) {
            int qrow = q0 + w * 16 + lg * 4 + r;
            out[((size_t)b * 1024 + qrow) * 1024 + h * 64 + d] = oacc[nt][r];
        }
    }
}

extern "C" void kernel_launch(void* const* d_in, const int* in_sizes, int n_in,
                              void* d_out, int out_size, void* d_ws, size_t ws_size,
                              hipStream_t stream) {
    const float* hs  = (const float*)d_in[0];
    const float* Wq  = (const float*)d_in[1];
    const float* bq  = (const float*)d_in[2];
    const float* Wk  = (const float*)d_in[3];
    const float* bk  = (const float*)d_in[4];
    const float* Wv  = (const float*)d_in[5];
    const float* bv  = (const float*)d_in[6];
    const float* rel = (const float*)d_in[7];
    float* out = (float*)d_out;
    char* ws = (char*)d_ws;

    uint16_t* hs_bf = (uint16_t*)(ws);                // 8 MB   [4096][1024]
    uint16_t* W_bf  = (uint16_t*)(ws + 8388608);      // 6 MB   [3][1024][1024]
    uint16_t* q_bf  = (uint16_t*)(ws + 14680064);     // 8 MB   [64][1024][64]
    uint16_t* k_bf  = (uint16_t*)(ws + 23068672);     // 8 MB
    uint16_t* v_bf  = (uint16_t*)(ws + 31457280);     // 8 MB
    uint16_t* vt_bf = (uint16_t*)(ws + 39845888);     // 8 MB   [64][64][1024]
    uint16_t* R_bf  = (uint16_t*)(ws + 48234496);     // 32 MB  [65536][256]
    uint16_t* tab   = (uint16_t*)(ws + 81788928);     // 32 KB  [256][64]
    uint16_t* tabT  = (uint16_t*)(ws + 81821696);     // 32 KB  [64][256]
    float*    m_buf = (float*)(ws + 81854464);        // 256 KB [65536]
    float*    l_buf = (float*)(ws + 82116608);        // 256 KB

    k_cast_bf16<<<2048, 256, 0, stream>>>(hs, hs_bf, 524288);
    k_cast_bf16<<<512, 256, 0, stream>>>(Wq, W_bf, 131072);
    k_cast_bf16<<<512, 256, 0, stream>>>(Wk, W_bf + 1048576, 131072);
    k_cast_bf16<<<512, 256, 0, stream>>>(Wv, W_bf + 2097152, 131072);
    k_table<<<1, 256, 0, stream>>>(rel, tab, tabT);

    k_gemm_qkv<<<dim3(32, 8), 256, 0, stream>>>(hs_bf, W_bf, bq, q_bf);
    k_gemm_qkv<<<dim3(32, 8), 256, 0, stream>>>(hs_bf, W_bf + 1048576, bk, k_bf);
    k_gemm_qkv<<<dim3(32, 8), 256, 0, stream>>>(hs_bf, W_bf + 2097152, bv, v_bf);

    k_transpose_v<<<1024, 256, 0, stream>>>(v_bf, vt_bf);
    k_r_gemm<<<1024, 256, 0, stream>>>(q_bf, tab, R_bf);

    k_attn_ml<<<1024, 256, 0, stream>>>(q_bf, k_bf, R_bf, m_buf, l_buf);
    k_attn_out<<<1024, 256, 0, stream>>>(q_bf, k_bf, vt_bf, R_bf, tabT, m_buf, l_buf, out);
}

// Round 2
// 320.630 us; speedup vs baseline: 1.2541x; 1.2541x over previous
//
#include <hip/hip_runtime.h>
#include <stdint.h>

// NeZha self-attention, B=4 S=1024 H=1024 NH=16 HD=64 MAX_REL=127.
// rel_pos[q,k,:] == table[clip(k-q,-127,127)+127,:], table is 255x64.
//  - score rel term:  gather from R = Q @ table^T  (R[q, j] per (b,h))
//  - ctx rel term:    Pagg @ table, Pagg = banded prob aggregation (bijective
//    for |k-q|<127; clipped tails accumulated in registers)
// Two-pass softmax: pass A -> exact (m,l); pass B -> P, O=P@V + Pagg@table.
// Swapped QK^T (mfma(K,Q) -> S^T) so each lane owns ONE q-row: softmax state
// and Pagg tails are per-lane scalars; Ps writes are aligned b64.
// K/V/Q fragments load direct from global (L2-hot) -> no barriers in k-loop.

typedef __bf16 bf16x8 __attribute__((ext_vector_type(8)));
typedef float f32x4 __attribute__((ext_vector_type(4)));
typedef uint16_t u16x8 __attribute__((ext_vector_type(8)));
typedef uint16_t u16x4 __attribute__((ext_vector_type(4)));

__device__ __forceinline__ uint16_t f2bf(float f) {
    uint32_t u = __builtin_bit_cast(uint32_t, f);
    return (uint16_t)((u + 0x7FFFu + ((u >> 16) & 1u)) >> 16);
}
__device__ __forceinline__ float bf2f(uint16_t h) {
    uint32_t u = ((uint32_t)h) << 16;
    return __builtin_bit_cast(float, u);
}
__device__ __forceinline__ f32x4 mfma16(bf16x8 a, bf16x8 b, f32x4 c) {
    return __builtin_amdgcn_mfma_f32_16x16x32_bf16(a, b, c, 0, 0, 0);
}
__device__ __forceinline__ bf16x8 ldg8(const uint16_t* p) {
    return __builtin_bit_cast(bf16x8, *(const u16x8*)p);
}

// ---------------- cast fp32 -> bf16 (8 elems/thread) ----------------
__global__ void k_cast_bf16(const float* __restrict__ in, uint16_t* __restrict__ out, int n8) {
    int i = blockIdx.x * 256 + threadIdx.x;
    if (i >= n8) return;
    float4 a = ((const float4*)in)[2 * i];
    float4 b = ((const float4*)in)[2 * i + 1];
    u16x8 o;
    o[0] = f2bf(a.x); o[1] = f2bf(a.y); o[2] = f2bf(a.z); o[3] = f2bf(a.w);
    o[4] = f2bf(b.x); o[5] = f2bf(b.y); o[6] = f2bf(b.z); o[7] = f2bf(b.w);
    ((u16x8*)out)[i] = o;
}

// ---------------- extract sinusoid table from rel_pos ----------------
__global__ void k_table(const float* __restrict__ rel, uint16_t* __restrict__ tab,
                        uint16_t* __restrict__ tabT) {
    for (int idx = threadIdx.x; idx < 256 * 64; idx += 256) {
        int j = idx >> 6, d = idx & 63;
        float v = 0.0f;
        if (j < 255) v = rel[((size_t)512 * 1024 + (512 + j - 127)) * 64 + d];
        uint16_t h = f2bf(v);
        tab[j * 64 + d] = h;       // [256][64]
        tabT[d * 256 + j] = h;     // [64][256]
    }
}

// ---------------- QKV projection GEMM: 128x128 tile, BK=64 ----------------
__launch_bounds__(256)
__global__ void k_gemm_qkv(const uint16_t* __restrict__ A, const uint16_t* __restrict__ Wt,
                           const float* __restrict__ bias, uint16_t* __restrict__ dst) {
    __shared__ uint16_t As[128 * 72];
    __shared__ uint16_t Bs[128 * 72];
    int m0 = blockIdx.x * 128, n0 = blockIdx.y * 128;
    int tid = threadIdx.x;
    int w = tid >> 6, l = tid & 63, lg = l >> 4, ln = l & 15;
    int wm = w >> 1, wn = w & 1;
    f32x4 acc[4][4] = {};
    for (int kt = 0; kt < 16; ++kt) {
        int k0 = kt * 64;
        __syncthreads();
#pragma unroll
        for (int c = 0; c < 4; ++c) {
            int idx = c * 256 + tid;
            int row = idx >> 3, seg = idx & 7;
            *(u16x8*)&As[row * 72 + seg * 8] =
                *(const u16x8*)(A + (size_t)(m0 + row) * 1024 + k0 + seg * 8);
            *(u16x8*)&Bs[row * 72 + seg * 8] =
                *(const u16x8*)(Wt + (size_t)(n0 + row) * 1024 + k0 + seg * 8);
        }
        __syncthreads();
#pragma unroll
        for (int ks = 0; ks < 2; ++ks) {
            bf16x8 af[4], bfr[4];
#pragma unroll
            for (int mi = 0; mi < 4; ++mi)
                af[mi] = ldg8(&As[(wm * 64 + mi * 16 + ln) * 72 + ks * 32 + lg * 8]);
#pragma unroll
            for (int ni = 0; ni < 4; ++ni)
                bfr[ni] = ldg8(&Bs[(wn * 64 + ni * 16 + ln) * 72 + ks * 32 + lg * 8]);
#pragma unroll
            for (int mi = 0; mi < 4; ++mi)
#pragma unroll
                for (int ni = 0; ni < 4; ++ni)
                    acc[mi][ni] = mfma16(af[mi], bfr[ni], acc[mi][ni]);
        }
    }
#pragma unroll
    for (int ni = 0; ni < 4; ++ni) {
        int n = n0 + wn * 64 + ni * 16 + ln;
        float bv = bias[n];
        int h = n >> 6, d = n & 63;
#pragma unroll
        for (int mi = 0; mi < 4; ++mi) {
#pragma unroll
            for (int r = 0; r < 4; ++r) {
                int mrow = m0 + wm * 64 + mi * 16 + lg * 4 + r;
                int b = mrow >> 10, s = mrow & 1023;
                dst[(((size_t)(b * 16 + h)) * 1024 + s) * 64 + d] =
                    f2bf(acc[mi][ni][r] + bv);
            }
        }
    }
}

// ---------------- V transpose: [bh][s][d] -> VT [bh][d][s] ----------------
__global__ void k_transpose_v(const uint16_t* __restrict__ v, uint16_t* __restrict__ vt) {
    __shared__ uint16_t T[64][72];
    int bid = blockIdx.x;
    int bh = bid >> 4, s0 = (bid & 15) * 64;
    int tid = threadIdx.x;
    int row = tid >> 2, c0 = (tid & 3) * 16;
    const uint16_t* src = v + ((size_t)bh * 1024 + s0 + row) * 64 + c0;
    u16x8 a = *(const u16x8*)src, b = *(const u16x8*)(src + 8);
#pragma unroll
    for (int e = 0; e < 8; ++e) { T[row][c0 + e] = a[e]; T[row][c0 + 8 + e] = b[e]; }
    __syncthreads();
    u16x8 o0, o1;
#pragma unroll
    for (int e = 0; e < 8; ++e) { o0[e] = T[c0 + e][row]; o1[e] = T[c0 + 8 + e][row]; }
    uint16_t* dstp = vt + ((size_t)bh * 64 + row) * 1024 + s0 + c0;
    *(u16x8*)dstp = o0;
    *(u16x8*)(dstp + 8) = o1;
}

// ---------------- R = Q @ table^T : [65536,64] @ [64,256] -> bf16 ----------
__launch_bounds__(256)
__global__ void k_r_gemm(const uint16_t* __restrict__ q, const uint16_t* __restrict__ tab,
                         uint16_t* __restrict__ R) {
    __shared__ uint16_t Qs[64 * 72];
    int m0 = blockIdx.x * 64;
    int tid = threadIdx.x;
    int w = tid >> 6, l = tid & 63, lg = l >> 4, ln = l & 15;
#pragma unroll
    for (int c = 0; c < 2; ++c) {
        int idx = c * 256 + tid; int row = idx >> 3, seg = idx & 7;
        *(u16x8*)&Qs[row * 72 + seg * 8] =
            *(const u16x8*)(q + (size_t)(m0 + row) * 64 + seg * 8);
    }
    __syncthreads();
    bf16x8 aq[4][2];
#pragma unroll
    for (int mi = 0; mi < 4; ++mi)
#pragma unroll
        for (int ks = 0; ks < 2; ++ks)
            aq[mi][ks] = ldg8(&Qs[(mi * 16 + ln) * 72 + ks * 32 + lg * 8]);
    f32x4 acc[4][4] = {};
#pragma unroll
    for (int ni = 0; ni < 4; ++ni) {
        int j = w * 64 + ni * 16 + ln;
#pragma unroll
        for (int ks = 0; ks < 2; ++ks) {
            bf16x8 bt = ldg8(tab + j * 64 + ks * 32 + lg * 8);
#pragma unroll
            for (int mi = 0; mi < 4; ++mi)
                acc[mi][ni] = mfma16(aq[mi][ks], bt, acc[mi][ni]);
        }
    }
#pragma unroll
    for (int ni = 0; ni < 4; ++ni)
#pragma unroll
        for (int mi = 0; mi < 4; ++mi)
#pragma unroll
            for (int r = 0; r < 4; ++r)
                R[(size_t)(m0 + mi * 16 + lg * 4 + r) * 256 + w * 64 + ni * 16 + ln] =
                    f2bf(acc[mi][ni][r]);
}

// ---------------- pass A: exact row max m and denom l ----------------
// Swapped QK^T: lane owns one q-row (q = q0 + w*16 + ln). Barrier-free k-loop.
__launch_bounds__(256)
__global__ void k_attn_ml(const uint16_t* __restrict__ qb, const uint16_t* __restrict__ kb,
                          const uint16_t* __restrict__ Rb, float* __restrict__ mout,
                          float* __restrict__ lout) {
    __shared__ uint16_t Rs[64 * 264];
    int bid = blockIdx.x;
    bid = (bid & 7) * 128 + (bid >> 3);  // XCD-bijective swizzle (1024 wgs)
    int bh = bid >> 4, q0 = (bid & 15) * 64;
    int tid = threadIdx.x;
    int w = tid >> 6, l = tid & 63, lg = l >> 4, ln = l & 15;
    int qg = q0 + w * 16 + ln;           // this lane's q row (within bh)
    const uint16_t* rbase = Rb + ((size_t)bh * 1024 + q0) * 256;
#pragma unroll
    for (int c = 0; c < 8; ++c) {
        int idx = c * 256 + tid; int row = idx >> 5, seg = idx & 31;
        *(u16x8*)&Rs[row * 264 + seg * 8] = *(const u16x8*)(rbase + row * 256 + seg * 8);
    }
    __syncthreads();
    bf16x8 qf[2];
    const uint16_t* qrow = qb + ((size_t)bh * 1024 + qg) * 64;
#pragma unroll
    for (int ks = 0; ks < 2; ++ks) qf[ks] = ldg8(qrow + ks * 32 + lg * 8);
    float rell_s = bf2f(Rs[(w * 16 + ln) * 264 + 0]) * 0.125f;
    float relh_s = bf2f(Rs[(w * 16 + ln) * 264 + 254]) * 0.125f;
    float mloc = -1e30f, lloc = 0.f;
    for (int kt = 0; kt < 16; ++kt) {
        const uint16_t* kbase = kb + ((size_t)bh * 1024 + kt * 64) * 64;
        f32x4 acc[4] = {};
#pragma unroll
        for (int mt = 0; mt < 4; ++mt) {
#pragma unroll
            for (int ks = 0; ks < 2; ++ks) {
                bf16x8 a = ldg8(kbase + (size_t)(mt * 16 + ln) * 64 + ks * 32 + lg * 8);
                acc[mt] = mfma16(a, qf[ks], acc[mt]);
            }
        }
        float sv[16];
        if (kt * 64 - qg >= 127) {
#pragma unroll
            for (int mt = 0; mt < 4; ++mt)
#pragma unroll
                for (int r = 0; r < 4; ++r) sv[mt * 4 + r] = fmaf(acc[mt][r], 0.125f, relh_s);
        } else if (kt * 64 + 63 - qg <= -127) {
#pragma unroll
            for (int mt = 0; mt < 4; ++mt)
#pragma unroll
                for (int r = 0; r < 4; ++r) sv[mt * 4 + r] = fmaf(acc[mt][r], 0.125f, rell_s);
        } else {
#pragma unroll
            for (int mt = 0; mt < 4; ++mt)
#pragma unroll
                for (int r = 0; r < 4; ++r) {
                    int dj = kt * 64 + mt * 16 + lg * 4 + r - qg;
                    int djc = dj < -127 ? -127 : (dj > 127 ? 127 : dj);
                    float rel = bf2f(Rs[(w * 16 + ln) * 264 + djc + 127]);
                    sv[mt * 4 + r] = (acc[mt][r] + rel) * 0.125f;
                }
        }
        float tm = sv[0];
#pragma unroll
        for (int i = 1; i < 16; ++i) tm = fmaxf(tm, sv[i]);
        float mnew = fmaxf(mloc, tm);
        float se = 0.f;
#pragma unroll
        for (int i = 0; i < 16; ++i) se += __expf(sv[i] - mnew);
        lloc = lloc * __expf(mloc - mnew) + se;
        mloc = mnew;
    }
    // merge the 4 lanes (lg groups) that share this q-row
#pragma unroll
    for (int msk = 16; msk <= 32; msk <<= 1) {
        float m2 = __shfl_xor(mloc, msk);
        float l2 = __shfl_xor(lloc, msk);
        float mn = fmaxf(mloc, m2);
        lloc = lloc * __expf(mloc - mn) + l2 * __expf(m2 - mn);
        mloc = mn;
    }
    if ((l >> 4) == 0) {
        int gi = bh * 1024 + qg;
        mout[gi] = mloc;
        lout[gi] = lloc;
    }
}

// ---------------- pass B: P, O = P@V + Pagg@table ----------------
__launch_bounds__(256, 2)
__global__ void k_attn_out(const uint16_t* __restrict__ qb, const uint16_t* __restrict__ kb,
                           const uint16_t* __restrict__ vtb, const uint16_t* __restrict__ Rb,
                           const uint16_t* __restrict__ tabT, const float* __restrict__ mbuf,
                           const float* __restrict__ lbuf, float* __restrict__ out) {
    __shared__ uint16_t Rs[64 * 264];    // 33792 B
    __shared__ uint16_t Ps[64 * 72];     //  9216 B (rows wave-private)
    __shared__ uint16_t Pagg[64 * 272];  // 34816 B bf16 (rows wave-private)
    int bid = blockIdx.x;
    bid = (bid & 7) * 128 + (bid >> 3);  // XCD-bijective swizzle
    int bh = bid >> 4, q0 = (bid & 15) * 64;
    int tid = threadIdx.x;
    int w = tid >> 6, l = tid & 63, lg = l >> 4, ln = l & 15;
    int qg = q0 + w * 16 + ln;
    const uint16_t* rbase = Rb + ((size_t)bh * 1024 + q0) * 256;
#pragma unroll
    for (int c = 0; c < 8; ++c) {
        int idx = c * 256 + tid; int row = idx >> 5, seg = idx & 31;
        *(u16x8*)&Rs[row * 264 + seg * 8] = *(const u16x8*)(rbase + row * 256 + seg * 8);
    }
    for (int idx = tid; idx < 64 * 272 / 8; idx += 256) ((u16x8*)Pagg)[idx] = (u16x8)0;
    __syncthreads();
    bf16x8 qf[2];
    const uint16_t* qrow = qb + ((size_t)bh * 1024 + qg) * 64;
#pragma unroll
    for (int ks = 0; ks < 2; ++ks) qf[ks] = ldg8(qrow + ks * 32 + lg * 8);
    float rell_s = bf2f(Rs[(w * 16 + ln) * 264 + 0]) * 0.125f;
    float relh_s = bf2f(Rs[(w * 16 + ln) * 264 + 254]) * 0.125f;
    float mreg = mbuf[bh * 1024 + qg];
    float rinv = 1.0f / lbuf[bh * 1024 + qg];
    float slo = 0.f, shi = 0.f;
    f32x4 oacc[4] = {};
    for (int kt = 0; kt < 16; ++kt) {
        const uint16_t* kbase = kb + ((size_t)bh * 1024 + kt * 64) * 64;
        const uint16_t* vtbase = vtb + (size_t)bh * 64 * 1024 + kt * 64;
        // V fragments early (independent of P) so latency hides under QK^T+softmax
        bf16x8 bv[4][2];
#pragma unroll
        for (int nt = 0; nt < 4; ++nt)
#pragma unroll
            for (int ks = 0; ks < 2; ++ks)
                bv[nt][ks] = ldg8(vtbase + (size_t)(nt * 16 + ln) * 1024 + ks * 32 + lg * 8);
        f32x4 acc[4] = {};
#pragma unroll
        for (int mt = 0; mt < 4; ++mt)
#pragma unroll
            for (int ks = 0; ks < 2; ++ks) {
                bf16x8 a = ldg8(kbase + (size_t)(mt * 16 + ln) * 64 + ks * 32 + lg * 8);
                acc[mt] = mfma16(a, qf[ks], acc[mt]);
            }
        // P = exp(s - m)/l, write P^T row-chunks (aligned b64), aggregate Pagg
        if (kt * 64 - qg >= 127) {
#pragma unroll
            for (int mt = 0; mt < 4; ++mt) {
                u16x4 pv; float ps = 0.f;
#pragma unroll
                for (int r = 0; r < 4; ++r) {
                    float P = __expf(fmaf(acc[mt][r], 0.125f, relh_s) - mreg) * rinv;
                    pv[r] = f2bf(P); ps += P;
                }
                shi += ps;
                *(u16x4*)&Ps[(w * 16 + ln) * 72 + mt * 16 + lg * 4] = pv;
            }
        } else if (kt * 64 + 63 - qg <= -127) {
#pragma unroll
            for (int mt = 0; mt < 4; ++mt) {
                u16x4 pv; float ps = 0.f;
#pragma unroll
                for (int r = 0; r < 4; ++r) {
                    float P = __expf(fmaf(acc[mt][r], 0.125f, rell_s) - mreg) * rinv;
                    pv[r] = f2bf(P); ps += P;
                }
                slo += ps;
                *(u16x4*)&Ps[(w * 16 + ln) * 72 + mt * 16 + lg * 4] = pv;
            }
        } else {
#pragma unroll
            for (int mt = 0; mt < 4; ++mt) {
                u16x4 pv;
#pragma unroll
                for (int r = 0; r < 4; ++r) {
                    int dj = kt * 64 + mt * 16 + lg * 4 + r - qg;
                    int djc = dj < -127 ? -127 : (dj > 127 ? 127 : dj);
                    float rel = bf2f(Rs[(w * 16 + ln) * 264 + djc + 127]);
                    float P = __expf((acc[mt][r] + rel) * 0.125f - mreg) * rinv;
                    uint16_t h = f2bf(P);
                    pv[r] = h;
                    if (dj <= -127) slo += P;
                    else if (dj >= 127) shi += P;
                    else Pagg[(w * 16 + ln) * 272 + dj + 127] = h;
                }
                *(u16x4*)&Ps[(w * 16 + ln) * 72 + mt * 16 + lg * 4] = pv;
            }
        }
        // O += P @ V (wave-private Ps rows; intra-wave LDS ordering, no barrier)
#pragma unroll
        for (int ks = 0; ks < 2; ++ks) {
            bf16x8 ap = ldg8(&Ps[(w * 16 + ln) * 72 + ks * 32 + lg * 8]);
#pragma unroll
            for (int nt = 0; nt < 4; ++nt)
                oacc[nt] = mfma16(ap, bv[nt][ks], oacc[nt]);
        }
    }
    // clipped-tail columns: reduce the 4 lanes sharing this q-row
    slo += __shfl_xor(slo, 16); slo += __shfl_xor(slo, 32);
    shi += __shfl_xor(shi, 16); shi += __shfl_xor(shi, 32);
    if ((l >> 4) == 0) {
        Pagg[(w * 16 + ln) * 272 + 0] = f2bf(slo);
        Pagg[(w * 16 + ln) * 272 + 254] = f2bf(shi);
    }
    // O += Pagg @ table (B^T = tabT[d][j])
#pragma unroll
    for (int ks = 0; ks < 8; ++ks) {
        bf16x8 ap = ldg8(&Pagg[(w * 16 + ln) * 272 + ks * 32 + lg * 8]);
#pragma unroll
        for (int nt = 0; nt < 4; ++nt) {
            bf16x8 bt = ldg8(tabT + (size_t)(nt * 16 + ln) * 256 + ks * 32 + lg * 8);
            oacc[nt] = mfma16(ap, bt, oacc[nt]);
        }
    }
    int b = bh >> 4, h = bh & 15;
#pragma unroll
    for (int nt = 0; nt < 4; ++nt) {
#pragma unroll
        for (int r = 0; r < 4; ++r) {
            int qrow_o = q0 + w * 16 + lg * 4 + r;
            out[((size_t)b * 1024 + qrow_o) * 1024 + h * 64 + nt * 16 + ln] = oacc[nt][r];
        }
    }
}

extern "C" void kernel_launch(void* const* d_in, const int* in_sizes, int n_in,
                              void* d_out, int out_size, void* d_ws, size_t ws_size,
                              hipStream_t stream) {
    const float* hs  = (const float*)d_in[0];
    const float* Wq  = (const float*)d_in[1];
    const float* bq  = (const float*)d_in[2];
    const float* Wk  = (const float*)d_in[3];
    const float* bk  = (const float*)d_in[4];
    const float* Wv  = (const float*)d_in[5];
    const float* bv  = (const float*)d_in[6];
    const float* rel = (const float*)d_in[7];
    float* out = (float*)d_out;
    char* ws = (char*)d_ws;

    uint16_t* hs_bf = (uint16_t*)(ws);                // 8 MB   [4096][1024]
    uint16_t* W_bf  = (uint16_t*)(ws + 8388608);      // 6 MB   [3][1024][1024]
    uint16_t* q_bf  = (uint16_t*)(ws + 14680064);     // 8 MB   [64][1024][64]
    uint16_t* k_bf  = (uint16_t*)(ws + 23068672);     // 8 MB
    uint16_t* v_bf  = (uint16_t*)(ws + 31457280);     // 8 MB
    uint16_t* vt_bf = (uint16_t*)(ws + 39845888);     // 8 MB   [64][64][1024]
    uint16_t* R_bf  = (uint16_t*)(ws + 48234496);     // 32 MB  [65536][256]
    uint16_t* tab   = (uint16_t*)(ws + 81788928);     // 32 KB  [256][64]
    uint16_t* tabT  = (uint16_t*)(ws + 81821696);     // 32 KB  [64][256]
    float*    m_buf = (float*)(ws + 81854464);        // 256 KB [65536]
    float*    l_buf = (float*)(ws + 82116608);        // 256 KB

    k_cast_bf16<<<2048, 256, 0, stream>>>(hs, hs_bf, 524288);
    k_cast_bf16<<<512, 256, 0, stream>>>(Wq, W_bf, 131072);
    k_cast_bf16<<<512, 256, 0, stream>>>(Wk, W_bf + 1048576, 131072);
    k_cast_bf16<<<512, 256, 0, stream>>>(Wv, W_bf + 2097152, 131072);
    k_table<<<1, 256, 0, stream>>>(rel, tab, tabT);

    k_gemm_qkv<<<dim3(32, 8), 256, 0, stream>>>(hs_bf, W_bf, bq, q_bf);
    k_gemm_qkv<<<dim3(32, 8), 256, 0, stream>>>(hs_bf, W_bf + 1048576, bk, k_bf);
    k_gemm_qkv<<<dim3(32, 8), 256, 0, stream>>>(hs_bf, W_bf + 2097152, bv, v_bf);

    k_transpose_v<<<1024, 256, 0, stream>>>(v_bf, vt_bf);
    k_r_gemm<<<1024, 256, 0, stream>>>(q_bf, tab, R_bf);

    k_attn_ml<<<1024, 256, 0, stream>>>(q_bf, k_bf, R_bf, m_buf, l_buf);
    k_attn_out<<<1024, 256, 0, stream>>>(q_bf, k_bf, vt_bf, R_bf, tabT, m_buf, l_buf, out);
}

// Round 3
// 220.420 us; speedup vs baseline: 1.8242x; 1.4546x over previous
//
#include <hip/hip_runtime.h>
#include <stdint.h>

// NeZha self-attention, B=4 S=1024 H=1024 NH=16 HD=64 MAX_REL=127.
// rel_pos[q,k,:] == table[clip(k-q,-127,127)+127,:], table is 255x64.
//  - score rel term:  gather from R = Q @ table^T (computed IN-KERNEL per wave)
//  - ctx rel term:    Pagg @ table, Pagg = banded prob aggregation (bijective
//    for |k-q|<127; clipped tails in registers)
// Single-pass ONLINE softmax with defer-max (THR=8): rescales ~never fire on
// this data; when they do, oacc needs row-transposed factors via __shfl
// (O-fragment rows are lg*4+r, softmax state rows are ln).
// Barrier-free attention kernel: Rs/Ps/Pagg rows are all wave-private.

typedef __bf16 bf16x8 __attribute__((ext_vector_type(8)));
typedef float f32x4 __attribute__((ext_vector_type(4)));
typedef uint16_t u16x8 __attribute__((ext_vector_type(8)));
typedef uint16_t u16x4 __attribute__((ext_vector_type(4)));

__device__ __forceinline__ uint16_t f2bf(float f) {
    uint32_t u = __builtin_bit_cast(uint32_t, f);
    return (uint16_t)((u + 0x7FFFu + ((u >> 16) & 1u)) >> 16);
}
__device__ __forceinline__ float bf2f(uint16_t h) {
    uint32_t u = ((uint32_t)h) << 16;
    return __builtin_bit_cast(float, u);
}
__device__ __forceinline__ f32x4 mfma16(bf16x8 a, bf16x8 b, f32x4 c) {
    return __builtin_amdgcn_mfma_f32_16x16x32_bf16(a, b, c, 0, 0, 0);
}
__device__ __forceinline__ bf16x8 ldg8(const uint16_t* p) {
    return __builtin_bit_cast(bf16x8, *(const u16x8*)p);
}
__device__ __forceinline__ void gload16(const uint16_t* g, uint16_t* l) {
    __builtin_amdgcn_global_load_lds(
        (const __attribute__((address_space(1))) void*)g,
        (__attribute__((address_space(3))) void*)l, 16, 0, 0);
}

// ---------------- cast fp32 -> bf16 (8 elems/thread) ----------------
__global__ void k_cast_bf16(const float* __restrict__ in, uint16_t* __restrict__ out, int n8) {
    int i = blockIdx.x * 256 + threadIdx.x;
    if (i >= n8) return;
    float4 a = ((const float4*)in)[2 * i];
    float4 b = ((const float4*)in)[2 * i + 1];
    u16x8 o;
    o[0] = f2bf(a.x); o[1] = f2bf(a.y); o[2] = f2bf(a.z); o[3] = f2bf(a.w);
    o[4] = f2bf(b.x); o[5] = f2bf(b.y); o[6] = f2bf(b.z); o[7] = f2bf(b.w);
    ((u16x8*)out)[i] = o;
}

// ---------------- extract sinusoid table from rel_pos ----------------
__global__ void k_table(const float* __restrict__ rel, uint16_t* __restrict__ tab,
                        uint16_t* __restrict__ tabT) {
    int idx = blockIdx.x * 256 + threadIdx.x;  // 64 blocks x 256 = 16384
    int j = idx >> 6, d = idx & 63;
    float v = 0.0f;
    if (j < 255) v = rel[((size_t)512 * 1024 + (512 + j - 127)) * 64 + d];
    uint16_t h = f2bf(v);
    tab[j * 64 + d] = h;       // [256][64]
    tabT[d * 256 + j] = h;     // [64][256]
}

// ------- fused QKV GEMM: [4096,1024] @ [3072,1024]^T, global_load_lds staging -------
__launch_bounds__(256)
__global__ void k_gemm_qkv3(const uint16_t* __restrict__ A, const uint16_t* __restrict__ Wt,
                            const float* __restrict__ bq, const float* __restrict__ bk,
                            const float* __restrict__ bvp, uint16_t* __restrict__ qkv) {
    __shared__ uint16_t As[128 * 64];  // linear (no pad): required by global_load_lds
    __shared__ uint16_t Bs[128 * 64];
    int bid = blockIdx.x;
    int swz = (bid & 7) * 96 + (bid >> 3);  // XCD-bijective, 768 = 8*96
    int m0 = (swz & 31) * 128, n0 = (swz >> 5) * 128;
    int tid = threadIdx.x;
    int w = tid >> 6, l = tid & 63, lg = l >> 4, ln = l & 15;
    int wm = w >> 1, wn = w & 1;
    int lrow = tid >> 3, lcol = (tid & 7) * 8;  // lane-linear LDS dest (16B/lane)
    f32x4 acc[4][4] = {};
    for (int kt = 0; kt < 16; ++kt) {
        int k0 = kt * 64;
        __syncthreads();
#pragma unroll
        for (int c = 0; c < 4; ++c) {
            int row = c * 32 + lrow;
            gload16(A + (size_t)(m0 + row) * 1024 + k0 + lcol, &As[row * 64 + lcol]);
            gload16(Wt + (size_t)(n0 + row) * 1024 + k0 + lcol, &Bs[row * 64 + lcol]);
        }
        __syncthreads();
#pragma unroll
        for (int ks = 0; ks < 2; ++ks) {
            bf16x8 af[4], bfr[4];
#pragma unroll
            for (int mi = 0; mi < 4; ++mi)
                af[mi] = ldg8(&As[(wm * 64 + mi * 16 + ln) * 64 + ks * 32 + lg * 8]);
#pragma unroll
            for (int ni = 0; ni < 4; ++ni)
                bfr[ni] = ldg8(&Bs[(wn * 64 + ni * 16 + ln) * 64 + ks * 32 + lg * 8]);
#pragma unroll
            for (int mi = 0; mi < 4; ++mi)
#pragma unroll
                for (int ni = 0; ni < 4; ++ni)
                    acc[mi][ni] = mfma16(af[mi], bfr[ni], acc[mi][ni]);
        }
    }
#pragma unroll
    for (int ni = 0; ni < 4; ++ni) {
        int n = n0 + wn * 64 + ni * 16 + ln;
        int which = n >> 10, nr = n & 1023;
        const float* bp = which == 0 ? bq : (which == 1 ? bk : bvp);
        float bb = bp[nr];
        int h = nr >> 6, d = nr & 63;
        uint16_t* base = qkv + (size_t)which * 4194304;  // q,k,v contiguous 8MB apart
#pragma unroll
        for (int mi = 0; mi < 4; ++mi)
#pragma unroll
            for (int r = 0; r < 4; ++r) {
                int mrow = m0 + wm * 64 + mi * 16 + lg * 4 + r;
                int b = mrow >> 10, s = mrow & 1023;
                base[(((size_t)(b * 16 + h)) * 1024 + s) * 64 + d] = f2bf(acc[mi][ni][r] + bb);
            }
    }
}

// ---------------- V transpose: [bh][s][d] -> VT [bh][d][s] ----------------
__global__ void k_transpose_v(const uint16_t* __restrict__ v, uint16_t* __restrict__ vt) {
    __shared__ uint16_t T[64][72];
    int bid = blockIdx.x;
    int bh = bid >> 4, s0 = (bid & 15) * 64;
    int tid = threadIdx.x;
    int row = tid >> 2, c0 = (tid & 3) * 16;
    const uint16_t* src = v + ((size_t)bh * 1024 + s0 + row) * 64 + c0;
    u16x8 a = *(const u16x8*)src, b = *(const u16x8*)(src + 8);
#pragma unroll
    for (int e = 0; e < 8; ++e) { T[row][c0 + e] = a[e]; T[row][c0 + 8 + e] = b[e]; }
    __syncthreads();
    u16x8 o0, o1;
#pragma unroll
    for (int e = 0; e < 8; ++e) { o0[e] = T[c0 + e][row]; o1[e] = T[c0 + 8 + e][row]; }
    uint16_t* dstp = vt + ((size_t)bh * 64 + row) * 1024 + s0 + c0;
    *(u16x8*)dstp = o0;
    *(u16x8*)(dstp + 8) = o1;
}

// ---------------- fused attention: R in-LDS + online softmax + PV + Pagg@tab ------
__launch_bounds__(256, 2)
__global__ void k_attn_fused(const uint16_t* __restrict__ qb, const uint16_t* __restrict__ kb,
                             const uint16_t* __restrict__ vtb, const uint16_t* __restrict__ tab,
                             const uint16_t* __restrict__ tabT, float* __restrict__ out) {
    __shared__ uint16_t Rs[64 * 264];    // 33792 B, rows wave-private
    __shared__ uint16_t Ps[64 * 72];     //  9216 B, rows wave-private
    __shared__ uint16_t Pagg[64 * 264];  // 33792 B, rows wave-private
    int bid = blockIdx.x;
    bid = (bid & 7) * 128 + (bid >> 3);  // XCD-bijective swizzle (1024 wgs)
    int bh = bid >> 4, q0 = (bid & 15) * 64;
    int tid = threadIdx.x;
    int w = tid >> 6, l = tid & 63, lg = l >> 4, ln = l & 15;
    int qg = q0 + w * 16 + ln;  // this lane's softmax q-row
    bf16x8 qf[2];
    const uint16_t* qrow = qb + ((size_t)bh * 1024 + qg) * 64;
    qf[0] = ldg8(qrow + lg * 8);
    qf[1] = ldg8(qrow + 32 + lg * 8);
    {   // zero this wave's Pagg rows
        u16x8* pb = (u16x8*)&Pagg[w * 16 * 264];
        for (int i = l; i < 528; i += 64) pb[i] = (u16x8)0;
    }
    // R rows for this wave: R[q][j] = Q[q,:]·tab[j,:]  (wave-private -> no barrier)
#pragma unroll
    for (int jt = 0; jt < 16; ++jt) {
        f32x4 racc = {0.f, 0.f, 0.f, 0.f};
        bf16x8 tb0 = ldg8(tab + (size_t)(jt * 16 + ln) * 64 + lg * 8);
        bf16x8 tb1 = ldg8(tab + (size_t)(jt * 16 + ln) * 64 + 32 + lg * 8);
        racc = mfma16(qf[0], tb0, racc);
        racc = mfma16(qf[1], tb1, racc);
#pragma unroll
        for (int r = 0; r < 4; ++r)
            Rs[(w * 16 + lg * 4 + r) * 264 + jt * 16 + ln] = f2bf(racc[r]);
    }
    float rell_s = bf2f(Rs[(w * 16 + ln) * 264 + 0]) * 0.125f;
    float relh_s = bf2f(Rs[(w * 16 + ln) * 264 + 254]) * 0.125f;
    float mref = -1e30f, lloc = 0.f, slo = 0.f, shi = 0.f;
    f32x4 oacc[4] = {};
    for (int kt = 0; kt < 16; ++kt) {
        const uint16_t* kbase = kb + ((size_t)bh * 1024 + kt * 64) * 64;
        const uint16_t* vtbase = vtb + (size_t)bh * 64 * 1024 + kt * 64;
        bf16x8 bv[4][2];  // V frags early: latency hides under QK^T+softmax
#pragma unroll
        for (int nt = 0; nt < 4; ++nt) {
            bv[nt][0] = ldg8(vtbase + (size_t)(nt * 16 + ln) * 1024 + lg * 8);
            bv[nt][1] = ldg8(vtbase + (size_t)(nt * 16 + ln) * 1024 + 32 + lg * 8);
        }
        f32x4 acc[4] = {};  // S^T: row=k (mt*16+lg*4+r), col=q (ln)
#pragma unroll
        for (int mt = 0; mt < 4; ++mt) {
            bf16x8 a0 = ldg8(kbase + (size_t)(mt * 16 + ln) * 64 + lg * 8);
            bf16x8 a1 = ldg8(kbase + (size_t)(mt * 16 + ln) * 64 + 32 + lg * 8);
            acc[mt] = mfma16(a0, qf[0], acc[mt]);
            acc[mt] = mfma16(a1, qf[1], acc[mt]);
        }
        int cls = (kt * 64 - qg >= 127) ? 2 : ((kt * 64 + 63 - qg <= -127) ? 0 : 1);
        float sv[16];
        if (cls == 2) {
#pragma unroll
            for (int mt = 0; mt < 4; ++mt)
#pragma unroll
                for (int r = 0; r < 4; ++r) sv[mt * 4 + r] = fmaf(acc[mt][r], 0.125f, relh_s);
        } else if (cls == 0) {
#pragma unroll
            for (int mt = 0; mt < 4; ++mt)
#pragma unroll
                for (int r = 0; r < 4; ++r) sv[mt * 4 + r] = fmaf(acc[mt][r], 0.125f, rell_s);
        } else {
#pragma unroll
            for (int mt = 0; mt < 4; ++mt)
#pragma unroll
                for (int r = 0; r < 4; ++r) {
                    int dj = kt * 64 + mt * 16 + lg * 4 + r - qg;
                    int djc = dj < -127 ? -127 : (dj > 127 ? 127 : dj);
                    float rel = bf2f(Rs[(w * 16 + ln) * 264 + djc + 127]);
                    sv[mt * 4 + r] = (acc[mt][r] + rel) * 0.125f;
                }
        }
        float tm = sv[0];
#pragma unroll
        for (int i = 1; i < 16; ++i) tm = fmaxf(tm, sv[i]);
        tm = fmaxf(tm, __shfl_xor(tm, 16));   // merge 4 replicas of this q-row
        tm = fmaxf(tm, __shfl_xor(tm, 32));
        bool need = tm > mref + 8.0f;         // defer-max THR=8 (fires ~only at kt=0)
        if (__any(need)) {
            float f = need ? __expf(mref - tm) : 1.0f;
#pragma unroll
            for (int r = 0; r < 4; ++r) {     // oacc rows are lg*4+r: transpose factors
                float fr = __shfl(f, lg * 4 + r);
#pragma unroll
                for (int nt = 0; nt < 4; ++nt) oacc[nt][r] *= fr;
            }
            if (need) {
                lloc *= f; slo *= f; shi *= f;
                uint16_t* prow = &Pagg[(w * 16 + ln) * 264 + lg * 64];  // replicas split row
#pragma unroll
                for (int c = 0; c < 8; ++c) {
                    u16x8 pv8 = *(u16x8*)&prow[c * 8];
#pragma unroll
                    for (int e = 0; e < 8; ++e) pv8[e] = f2bf(bf2f(pv8[e]) * f);
                    *(u16x8*)&prow[c * 8] = pv8;
                }
                mref = tm;
            }
        }
        // P (unnormalized, <= e^8) + aggregation
        if (cls == 1) {
#pragma unroll
            for (int mt = 0; mt < 4; ++mt) {
                u16x4 pv;
#pragma unroll
                for (int r = 0; r < 4; ++r) {
                    int dj = kt * 64 + mt * 16 + lg * 4 + r - qg;
                    float P = __expf(sv[mt * 4 + r] - mref);
                    lloc += P;
                    uint16_t h = f2bf(P);
                    pv[r] = h;
                    if (dj <= -127) slo += P;
                    else if (dj >= 127) shi += P;
                    else Pagg[(w * 16 + ln) * 264 + dj + 127] = h;
                }
                *(u16x4*)&Ps[(w * 16 + ln) * 72 + mt * 16 + lg * 4] = pv;
            }
        } else {
            float ts = 0.f;
#pragma unroll
            for (int mt = 0; mt < 4; ++mt) {
                u16x4 pv;
#pragma unroll
                for (int r = 0; r < 4; ++r) {
                    float P = __expf(sv[mt * 4 + r] - mref);
                    lloc += P; ts += P;
                    pv[r] = f2bf(P);
                }
                *(u16x4*)&Ps[(w * 16 + ln) * 72 + mt * 16 + lg * 4] = pv;
            }
            if (cls == 2) shi += ts; else slo += ts;
        }
        // O += P @ V (wave-private Ps rows; wave-synchronous, no barrier)
#pragma unroll
        for (int ks = 0; ks < 2; ++ks) {
            bf16x8 ap = ldg8(&Ps[(w * 16 + ln) * 72 + ks * 32 + lg * 8]);
#pragma unroll
            for (int nt = 0; nt < 4; ++nt)
                oacc[nt] = mfma16(ap, bv[nt][ks], oacc[nt]);
        }
    }
    lloc += __shfl_xor(lloc, 16); lloc += __shfl_xor(lloc, 32);
    slo  += __shfl_xor(slo, 16);  slo  += __shfl_xor(slo, 32);
    shi  += __shfl_xor(shi, 16);  shi  += __shfl_xor(shi, 32);
    if (lg == 0) {
        Pagg[(w * 16 + ln) * 264 + 0]   = f2bf(slo);
        Pagg[(w * 16 + ln) * 264 + 254] = f2bf(shi);
    }
    // O += Pagg @ table (B^T = tabT[d][j])
#pragma unroll
    for (int ks = 0; ks < 8; ++ks) {
        bf16x8 ap = ldg8(&Pagg[(w * 16 + ln) * 264 + ks * 32 + lg * 8]);
#pragma unroll
        for (int nt = 0; nt < 4; ++nt) {
            bf16x8 bt = ldg8(tabT + (size_t)(nt * 16 + ln) * 256 + ks * 32 + lg * 8);
            oacc[nt] = mfma16(ap, bt, oacc[nt]);
        }
    }
    float rinv[4];  // 1/l for oacc's rows (lg*4+r), fetched from replica 0 lanes
#pragma unroll
    for (int r = 0; r < 4; ++r) rinv[r] = 1.0f / __shfl(lloc, lg * 4 + r);
    int b = bh >> 4, h = bh & 15;
#pragma unroll
    for (int nt = 0; nt < 4; ++nt) {
#pragma unroll
        for (int r = 0; r < 4; ++r) {
            int qo = q0 + w * 16 + lg * 4 + r;
            out[((size_t)b * 1024 + qo) * 1024 + h * 64 + nt * 16 + ln] = oacc[nt][r] * rinv[r];
        }
    }
}

extern "C" void kernel_launch(void* const* d_in, const int* in_sizes, int n_in,
                              void* d_out, int out_size, void* d_ws, size_t ws_size,
                              hipStream_t stream) {
    const float* hs  = (const float*)d_in[0];
    const float* Wq  = (const float*)d_in[1];
    const float* bq  = (const float*)d_in[2];
    const float* Wk  = (const float*)d_in[3];
    const float* bk  = (const float*)d_in[4];
    const float* Wv  = (const float*)d_in[5];
    const float* bv  = (const float*)d_in[6];
    const float* rel = (const float*)d_in[7];
    float* out = (float*)d_out;
    char* ws = (char*)d_ws;

    uint16_t* hs_bf = (uint16_t*)(ws);                // 8 MB   [4096][1024]
    uint16_t* W_bf  = (uint16_t*)(ws + 8388608);      // 6 MB   [3072][1024]
    uint16_t* q_bf  = (uint16_t*)(ws + 14680064);     // 8 MB   [64][1024][64]  (q,k,v contiguous)
    uint16_t* v_bf  = (uint16_t*)(ws + 31457280);     // 8 MB
    uint16_t* vt_bf = (uint16_t*)(ws + 39845888);     // 8 MB   [64][64][1024]
    uint16_t* tab   = (uint16_t*)(ws + 81788928);     // 32 KB  [256][64]
    uint16_t* tabT  = (uint16_t*)(ws + 81821696);     // 32 KB  [64][256]
    uint16_t* k_bf  = q_bf + 4194304;

    k_cast_bf16<<<2048, 256, 0, stream>>>(hs, hs_bf, 524288);
    k_cast_bf16<<<512, 256, 0, stream>>>(Wq, W_bf, 131072);
    k_cast_bf16<<<512, 256, 0, stream>>>(Wk, W_bf + 1048576, 131072);
    k_cast_bf16<<<512, 256, 0, stream>>>(Wv, W_bf + 2097152, 131072);
    k_table<<<64, 256, 0, stream>>>(rel, tab, tabT);

    k_gemm_qkv3<<<768, 256, 0, stream>>>(hs_bf, W_bf, bq, bk, bv, q_bf);
    k_transpose_v<<<1024, 256, 0, stream>>>(v_bf, vt_bf);

    k_attn_fused<<<1024, 256, 0, stream>>>(q_bf, k_bf, vt_bf, tab, tabT, out);
}

// Round 4
// 165.218 us; speedup vs baseline: 2.4337x; 1.3341x over previous
//
#include <hip/hip_runtime.h>
#include <stdint.h>

// NeZha self-attention, B=4 S=1024 H=1024 NH=16 HD=64 MAX_REL=127.
// rel_pos[q,k,:] == table[clip(k-q,-127,127)+127,:], table is 255x64.
//  - score rel term:  gather from R = Q @ table^T (computed IN-KERNEL per wave)
//  - ctx rel term:    Pagg @ table (banded prob aggregation; clipped tails in regs)
// Single-pass online softmax, defer-max THR=8 (rescale ~only fires at kt=0).
// v4: K/V^T tiles staged in LDS (XOR-swizzled, reg-prefetch 1 tile ahead) shared
// by all 4 waves; P redistributed for PV via in-register __shfl exchange (no Ps).
// LDS = 32K(Rs) + 32K(Pagg) + 8K(K) + 8K(V) = 81920 B -> 2 blocks/CU.

typedef __bf16 bf16x8 __attribute__((ext_vector_type(8)));
typedef float f32x4 __attribute__((ext_vector_type(4)));
typedef uint16_t u16x8 __attribute__((ext_vector_type(8)));
typedef uint16_t u16x4 __attribute__((ext_vector_type(4)));

__device__ __forceinline__ uint16_t f2bf(float f) {
    uint32_t u = __builtin_bit_cast(uint32_t, f);
    return (uint16_t)((u + 0x7FFFu + ((u >> 16) & 1u)) >> 16);
}
__device__ __forceinline__ float bf2f(uint16_t h) {
    uint32_t u = ((uint32_t)h) << 16;
    return __builtin_bit_cast(float, u);
}
__device__ __forceinline__ f32x4 mfma16(bf16x8 a, bf16x8 b, f32x4 c) {
    return __builtin_amdgcn_mfma_f32_16x16x32_bf16(a, b, c, 0, 0, 0);
}
__device__ __forceinline__ bf16x8 ldg8(const uint16_t* p) {
    return __builtin_bit_cast(bf16x8, *(const u16x8*)p);
}
__device__ __forceinline__ bf16x8 lds8(const uint16_t* base, int byteoff) {
    return __builtin_bit_cast(bf16x8, *(const u16x8*)((const char*)base + byteoff));
}

// ---------------- cast fp32 -> bf16 (8 elems/thread) ----------------
__global__ void k_cast_bf16(const float* __restrict__ in, uint16_t* __restrict__ out, int n8) {
    int i = blockIdx.x * 256 + threadIdx.x;
    if (i >= n8) return;
    float4 a = ((const float4*)in)[2 * i];
    float4 b = ((const float4*)in)[2 * i + 1];
    u16x8 o;
    o[0] = f2bf(a.x); o[1] = f2bf(a.y); o[2] = f2bf(a.z); o[3] = f2bf(a.w);
    o[4] = f2bf(b.x); o[5] = f2bf(b.y); o[6] = f2bf(b.z); o[7] = f2bf(b.w);
    ((u16x8*)out)[i] = o;
}

// ---------------- extract sinusoid table from rel_pos ----------------
__global__ void k_table(const float* __restrict__ rel, uint16_t* __restrict__ tab,
                        uint16_t* __restrict__ tabT) {
    int idx = blockIdx.x * 256 + threadIdx.x;  // 64 blocks x 256
    int j = idx >> 6, d = idx & 63;
    float v = 0.0f;
    if (j < 255) v = rel[((size_t)512 * 1024 + (512 + j - 127)) * 64 + d];
    uint16_t h = f2bf(v);
    tab[j * 64 + d] = h;       // [256][64]
    tabT[d * 256 + j] = h;     // [64][256]
}

// ------- fused QKV GEMM, V written pre-transposed: vt[bh][d][s] -------
__launch_bounds__(256)
__global__ void k_gemm_qkv3(const uint16_t* __restrict__ A, const uint16_t* __restrict__ Wt,
                            const float* __restrict__ bq, const float* __restrict__ bk,
                            const float* __restrict__ bvp, uint16_t* __restrict__ qout,
                            uint16_t* __restrict__ kout, uint16_t* __restrict__ vt) {
    __shared__ uint16_t As[128 * 64];  // linear: required by global_load_lds
    __shared__ uint16_t Bs[128 * 64];
    int bid = blockIdx.x;
    int swz = (bid & 7) * 96 + (bid >> 3);  // XCD-bijective, 768 = 8*96
    int m0 = (swz & 31) * 128, n0 = (swz >> 5) * 128;
    int tid = threadIdx.x;
    int w = tid >> 6, l = tid & 63, lg = l >> 4, ln = l & 15;
    int wm = w >> 1, wn = w & 1;
    int lrow = tid >> 3, lcol = (tid & 7) * 8;
    f32x4 acc[4][4] = {};
    for (int kt = 0; kt < 16; ++kt) {
        int k0 = kt * 64;
        __syncthreads();
#pragma unroll
        for (int c = 0; c < 4; ++c) {
            int row = c * 32 + lrow;
            __builtin_amdgcn_global_load_lds(
                (const __attribute__((address_space(1))) void*)(A + (size_t)(m0 + row) * 1024 + k0 + lcol),
                (__attribute__((address_space(3))) void*)&As[row * 64 + lcol], 16, 0, 0);
            __builtin_amdgcn_global_load_lds(
                (const __attribute__((address_space(1))) void*)(Wt + (size_t)(n0 + row) * 1024 + k0 + lcol),
                (__attribute__((address_space(3))) void*)&Bs[row * 64 + lcol], 16, 0, 0);
        }
        __syncthreads();
#pragma unroll
        for (int ks = 0; ks < 2; ++ks) {
            bf16x8 af[4], bfr[4];
#pragma unroll
            for (int mi = 0; mi < 4; ++mi)
                af[mi] = ldg8(&As[(wm * 64 + mi * 16 + ln) * 64 + ks * 32 + lg * 8]);
#pragma unroll
            for (int ni = 0; ni < 4; ++ni)
                bfr[ni] = ldg8(&Bs[(wn * 64 + ni * 16 + ln) * 64 + ks * 32 + lg * 8]);
#pragma unroll
            for (int mi = 0; mi < 4; ++mi)
#pragma unroll
                for (int ni = 0; ni < 4; ++ni)
                    acc[mi][ni] = mfma16(af[mi], bfr[ni], acc[mi][ni]);
        }
    }
    int b = m0 >> 10, srow = (m0 & 1023) + wm * 64;
#pragma unroll
    for (int ni = 0; ni < 4; ++ni) {
        int n = n0 + wn * 64 + ni * 16 + ln;
        int which = n >> 10, nr = n & 1023;  // `which` uniform per block
        const float* bp = which == 0 ? bq : (which == 1 ? bk : bvp);
        float bb = bp[nr];
        int h = nr >> 6, d = nr & 63;
        if (which < 2) {
            uint16_t* base = which == 0 ? qout : kout;
#pragma unroll
            for (int mi = 0; mi < 4; ++mi)
#pragma unroll
                for (int r = 0; r < 4; ++r) {
                    int s = srow + mi * 16 + lg * 4 + r;
                    base[(((size_t)(b * 16 + h)) * 1024 + s) * 64 + d] = f2bf(acc[mi][ni][r] + bb);
                }
        } else {
#pragma unroll
            for (int mi = 0; mi < 4; ++mi) {
                int s0 = srow + mi * 16 + lg * 4;
                u16x4 pv;
#pragma unroll
                for (int r = 0; r < 4; ++r) pv[r] = f2bf(acc[mi][ni][r] + bb);
                *(u16x4*)&vt[(((size_t)(b * 16 + h)) * 64 + d) * 1024 + s0] = pv;
            }
        }
    }
}

// ---------------- fused attention ----------------
__launch_bounds__(256, 2)
__global__ void k_attn_fused(const uint16_t* __restrict__ qb, const uint16_t* __restrict__ kb,
                             const uint16_t* __restrict__ vtb, const uint16_t* __restrict__ tab,
                             const uint16_t* __restrict__ tabT, float* __restrict__ out) {
    __shared__ uint16_t Rs[64 * 256];    // 32768 B, rows wave-private
    __shared__ uint16_t Pagg[64 * 256];  // 32768 B, rows wave-private
    __shared__ uint16_t Kb[64 * 64];     //  8192 B, XOR-swizzled [k][d]
    __shared__ uint16_t Vb[64 * 64];     //  8192 B, XOR-swizzled V^T [d][k]
    int bid = blockIdx.x;
    bid = (bid & 7) * 128 + (bid >> 3);  // XCD-bijective swizzle (1024 wgs)
    int bh = bid >> 4, q0 = (bid & 15) * 64;
    int tid = threadIdx.x;
    int w = tid >> 6, l = tid & 63, lg = l >> 4, ln = l & 15;
    int qg = q0 + w * 16 + ln;  // this lane's softmax q-row
    bf16x8 qf[2];
    const uint16_t* qrow = qb + ((size_t)bh * 1024 + qg) * 64;
    qf[0] = ldg8(qrow + lg * 8);
    qf[1] = ldg8(qrow + 32 + lg * 8);
    {   // zero this wave's Pagg rows
        u16x8* pb = (u16x8*)&Pagg[w * 16 * 256];
        for (int i = l; i < 512; i += 64) pb[i] = (u16x8)0;
    }
    // R rows for this wave: R[q][j] = Q[q,:]·tab[j,:]  (wave-private, no barrier)
#pragma unroll
    for (int jt = 0; jt < 16; ++jt) {
        f32x4 racc = {0.f, 0.f, 0.f, 0.f};
        bf16x8 tb0 = ldg8(tab + (size_t)(jt * 16 + ln) * 64 + lg * 8);
        bf16x8 tb1 = ldg8(tab + (size_t)(jt * 16 + ln) * 64 + 32 + lg * 8);
        racc = mfma16(qf[0], tb0, racc);
        racc = mfma16(qf[1], tb1, racc);
#pragma unroll
        for (int r = 0; r < 4; ++r)
            Rs[(w * 16 + lg * 4 + r) * 256 + jt * 16 + ln] = f2bf(racc[r]);
    }
    float rell_s = bf2f(Rs[(w * 16 + ln) * 256 + 0]) * 0.125f;
    float relh_s = bf2f(Rs[(w * 16 + ln) * 256 + 254]) * 0.125f;
    // staging geometry (chunks of 16B; rows 0..31 for c0, 32..63 for c1)
    const int r0 = tid >> 3, c16 = tid & 7;
    const int r1 = 32 + r0;
    const int wa0 = (r0 * 128 + c16 * 16) ^ ((r0 & 7) << 4);
    const int wa1 = (r1 * 128 + c16 * 16) ^ ((r1 & 7) << 4);
    const uint16_t* kt_base = kb + ((size_t)bh * 1024) * 64;
    const uint16_t* vt_base = vtb + (size_t)bh * 64 * 1024;
    // prefetch tile 0
    u16x8 kc0 = *(const u16x8*)(kt_base + (size_t)r0 * 64 + c16 * 8);
    u16x8 kc1 = *(const u16x8*)(kt_base + (size_t)r1 * 64 + c16 * 8);
    u16x8 vc0 = *(const u16x8*)(vt_base + (size_t)r0 * 1024 + c16 * 8);
    u16x8 vc1 = *(const u16x8*)(vt_base + (size_t)r1 * 1024 + c16 * 8);
    float mref = -1e30f, lloc = 0.f, slo = 0.f, shi = 0.f;
    f32x4 oacc[4] = {};
    const int sA = ((lg & 1) << 5) + ln;  // producer lane (lg'=(lg&1)*2)
    for (int kt = 0; kt < 16; ++kt) {
        __syncthreads();  // previous tile's LDS reads complete
        *(u16x8*)((uint16_t*)((char*)Kb + wa0)) = kc0;
        *(u16x8*)((uint16_t*)((char*)Kb + wa1)) = kc1;
        *(u16x8*)((uint16_t*)((char*)Vb + wa0)) = vc0;
        *(u16x8*)((uint16_t*)((char*)Vb + wa1)) = vc1;
        __syncthreads();  // tile kt visible
        if (kt < 15) {    // issue prefetch for kt+1; latency hides under compute
            const uint16_t* kn = kt_base + (size_t)(kt + 1) * 64 * 64;
            const uint16_t* vn = vt_base + (kt + 1) * 64;
            kc0 = *(const u16x8*)(kn + (size_t)r0 * 64 + c16 * 8);
            kc1 = *(const u16x8*)(kn + (size_t)r1 * 64 + c16 * 8);
            vc0 = *(const u16x8*)(vn + (size_t)r0 * 1024 + c16 * 8);
            vc1 = *(const u16x8*)(vn + (size_t)r1 * 1024 + c16 * 8);
        }
        // QK^T (S^T): row=k (lg*4+r within mt), col=q (ln)
        f32x4 acc[4] = {};
#pragma unroll
        for (int mt = 0; mt < 4; ++mt) {
            int row = mt * 16 + ln;
            bf16x8 a0 = lds8(Kb, (row * 128 + lg * 16) ^ ((ln & 7) << 4));
            bf16x8 a1 = lds8(Kb, (row * 128 + (4 + lg) * 16) ^ ((ln & 7) << 4));
            acc[mt] = mfma16(a0, qf[0], acc[mt]);
            acc[mt] = mfma16(a1, qf[1], acc[mt]);
        }
        int cls = (kt * 64 - qg >= 127) ? 2 : ((kt * 64 + 63 - qg <= -127) ? 0 : 1);
        float sv[16];
        if (cls == 2) {
#pragma unroll
            for (int mt = 0; mt < 4; ++mt)
#pragma unroll
                for (int r = 0; r < 4; ++r) sv[mt * 4 + r] = fmaf(acc[mt][r], 0.125f, relh_s);
        } else if (cls == 0) {
#pragma unroll
            for (int mt = 0; mt < 4; ++mt)
#pragma unroll
                for (int r = 0; r < 4; ++r) sv[mt * 4 + r] = fmaf(acc[mt][r], 0.125f, rell_s);
        } else {
#pragma unroll
            for (int mt = 0; mt < 4; ++mt)
#pragma unroll
                for (int r = 0; r < 4; ++r) {
                    int dj = kt * 64 + mt * 16 + lg * 4 + r - qg;
                    int djc = dj < -127 ? -127 : (dj > 127 ? 127 : dj);
                    float rel = bf2f(Rs[(w * 16 + ln) * 256 + djc + 127]);
                    sv[mt * 4 + r] = (acc[mt][r] + rel) * 0.125f;
                }
        }
        float tm = sv[0];
#pragma unroll
        for (int i = 1; i < 16; ++i) tm = fmaxf(tm, sv[i]);
        tm = fmaxf(tm, __shfl_xor(tm, 16));
        tm = fmaxf(tm, __shfl_xor(tm, 32));
        bool need = tm > mref + 8.0f;  // defer-max THR=8
        if (__any(need)) {
            float f = need ? __expf(mref - tm) : 1.0f;
#pragma unroll
            for (int r = 0; r < 4; ++r) {  // oacc rows are lg*4+r: transpose factors
                float fr = __shfl(f, lg * 4 + r);
#pragma unroll
                for (int nt = 0; nt < 4; ++nt) oacc[nt][r] *= fr;
            }
            if (need) {
                lloc *= f; slo *= f; shi *= f;
                uint16_t* prow = &Pagg[(w * 16 + ln) * 256 + lg * 64];
#pragma unroll
                for (int c = 0; c < 8; ++c) {
                    u16x8 pv8 = *(u16x8*)&prow[c * 8];
#pragma unroll
                    for (int e = 0; e < 8; ++e) pv8[e] = f2bf(bf2f(pv8[e]) * f);
                    *(u16x8*)&prow[c * 8] = pv8;
                }
                mref = tm;
            }
        }
        // P (unnormalized) + aggregation
        float Pv[16];
        if (cls == 1) {
#pragma unroll
            for (int mt = 0; mt < 4; ++mt)
#pragma unroll
                for (int r = 0; r < 4; ++r) {
                    int dj = kt * 64 + mt * 16 + lg * 4 + r - qg;
                    float P = __expf(sv[mt * 4 + r] - mref);
                    lloc += P;
                    Pv[mt * 4 + r] = P;
                    if (dj <= -127) slo += P;
                    else if (dj >= 127) shi += P;
                    else Pagg[(w * 16 + ln) * 256 + dj + 127] = f2bf(P);
                }
        } else {
            float ts = 0.f;
#pragma unroll
            for (int i = 0; i < 16; ++i) {
                float P = __expf(sv[i] - mref);
                lloc += P; ts += P;
                Pv[i] = P;
            }
            if (cls == 2) shi += ts; else slo += ts;
        }
        // pack P to bf16 pairs: pk[mt] = {(r0,r1),(r2,r3)}
        uint32_t pk[4][2];
#pragma unroll
        for (int mt = 0; mt < 4; ++mt) {
            pk[mt][0] = (uint32_t)f2bf(Pv[mt * 4 + 0]) | ((uint32_t)f2bf(Pv[mt * 4 + 1]) << 16);
            pk[mt][1] = (uint32_t)f2bf(Pv[mt * 4 + 2]) | ((uint32_t)f2bf(Pv[mt * 4 + 3]) << 16);
        }
        // exchange: consumer lane (lg,ln) frag ks needs mt=2ks+(lg>>1),
        // e0..3 from producer lg'=(lg&1)*2 (lane sA), e4..7 from lg'+1 (sA+16)
#pragma unroll
        for (int ks = 0; ks < 2; ++ks) {
            uint32_t lo0 = __shfl((int)pk[2 * ks][0], sA);
            uint32_t lo1 = __shfl((int)pk[2 * ks][1], sA);
            uint32_t hi0 = __shfl((int)pk[2 * ks + 1][0], sA);
            uint32_t hi1 = __shfl((int)pk[2 * ks + 1][1], sA);
            uint32_t a0 = (lg & 2) ? hi0 : lo0;
            uint32_t a1 = (lg & 2) ? hi1 : lo1;
            lo0 = __shfl((int)pk[2 * ks][0], sA + 16);
            lo1 = __shfl((int)pk[2 * ks][1], sA + 16);
            hi0 = __shfl((int)pk[2 * ks + 1][0], sA + 16);
            hi1 = __shfl((int)pk[2 * ks + 1][1], sA + 16);
            uint32_t b0 = (lg & 2) ? hi0 : lo0;
            uint32_t b1 = (lg & 2) ? hi1 : lo1;
            uint32_t fr[4] = {a0, a1, b0, b1};
            bf16x8 ap = __builtin_bit_cast(bf16x8, fr);
#pragma unroll
            for (int nt = 0; nt < 4; ++nt) {
                int row = nt * 16 + ln;
                bf16x8 bv = lds8(Vb, (row * 128 + (ks * 4 + lg) * 16) ^ ((ln & 7) << 4));
                oacc[nt] = mfma16(ap, bv, oacc[nt]);
            }
        }
    }
    lloc += __shfl_xor(lloc, 16); lloc += __shfl_xor(lloc, 32);
    slo  += __shfl_xor(slo, 16);  slo  += __shfl_xor(slo, 32);
    shi  += __shfl_xor(shi, 16);  shi  += __shfl_xor(shi, 32);
    if (lg == 0) {
        Pagg[(w * 16 + ln) * 256 + 0]   = f2bf(slo);
        Pagg[(w * 16 + ln) * 256 + 254] = f2bf(shi);
    }
    // O += Pagg @ table (B^T = tabT[d][j])
#pragma unroll
    for (int ks = 0; ks < 8; ++ks) {
        bf16x8 ap = ldg8(&Pagg[(w * 16 + ln) * 256 + ks * 32 + lg * 8]);
#pragma unroll
        for (int nt = 0; nt < 4; ++nt) {
            bf16x8 bt = ldg8(tabT + (size_t)(nt * 16 + ln) * 256 + ks * 32 + lg * 8);
            oacc[nt] = mfma16(ap, bt, oacc[nt]);
        }
    }
    float rinv[4];
#pragma unroll
    for (int r = 0; r < 4; ++r) rinv[r] = 1.0f / __shfl(lloc, lg * 4 + r);
    int b = bh >> 4, h = bh & 15;
#pragma unroll
    for (int nt = 0; nt < 4; ++nt) {
#pragma unroll
        for (int r = 0; r < 4; ++r) {
            int qo = q0 + w * 16 + lg * 4 + r;
            out[((size_t)b * 1024 + qo) * 1024 + h * 64 + nt * 16 + ln] = oacc[nt][r] * rinv[r];
        }
    }
}

extern "C" void kernel_launch(void* const* d_in, const int* in_sizes, int n_in,
                              void* d_out, int out_size, void* d_ws, size_t ws_size,
                              hipStream_t stream) {
    const float* hs  = (const float*)d_in[0];
    const float* Wq  = (const float*)d_in[1];
    const float* bq  = (const float*)d_in[2];
    const float* Wk  = (const float*)d_in[3];
    const float* bk  = (const float*)d_in[4];
    const float* Wv  = (const float*)d_in[5];
    const float* bv  = (const float*)d_in[6];
    const float* rel = (const float*)d_in[7];
    float* out = (float*)d_out;
    char* ws = (char*)d_ws;

    uint16_t* hs_bf = (uint16_t*)(ws);                // 8 MB   [4096][1024]
    uint16_t* W_bf  = (uint16_t*)(ws + 8388608);      // 6 MB   [3072][1024]
    uint16_t* q_bf  = (uint16_t*)(ws + 14680064);     // 8 MB   [64][1024][64]
    uint16_t* k_bf  = (uint16_t*)(ws + 23068672);     // 8 MB   [64][1024][64]
    uint16_t* vt_bf = (uint16_t*)(ws + 31457280);     // 8 MB   [64][64][1024]
    uint16_t* tab   = (uint16_t*)(ws + 81788928);     // 32 KB  [256][64]
    uint16_t* tabT  = (uint16_t*)(ws + 81821696);     // 32 KB  [64][256]

    k_cast_bf16<<<2048, 256, 0, stream>>>(hs, hs_bf, 524288);
    k_cast_bf16<<<512, 256, 0, stream>>>(Wq, W_bf, 131072);
    k_cast_bf16<<<512, 256, 0, stream>>>(Wk, W_bf + 1048576, 131072);
    k_cast_bf16<<<512, 256, 0, stream>>>(Wv, W_bf + 2097152, 131072);
    k_table<<<64, 256, 0, stream>>>(rel, tab, tabT);

    k_gemm_qkv3<<<768, 256, 0, stream>>>(hs_bf, W_bf, bq, bk, bv, q_bf, k_bf, vt_bf);

    k_attn_fused<<<1024, 256, 0, stream>>>(q_bf, k_bf, vt_bf, tab, tabT, out);
}